// Round 1
// baseline (5870.839 us; speedup 1.0000x reference)
//
#include <hip/hip_runtime.h>
#include <hip/hip_bf16.h>
#include <math.h>

// ---------------------------------------------------------------------------
// R3: wide-tile GEMM (BM=64 x BN=512 x BK=32) for all N%512==0 GEMMs.
// N=512 fits in one block => A panel fetched from HBM exactly once
// (old 128x128 tile re-read A 4x across N-blocks; measured 550 MB fetch on
// the entity projection = 2x A after L3 absorption). Reg-staged prefetch
// (issue global loads for tile k+1 before MFMA of tile k, ds_write after the
// barrier) hides HBM latency at ~1 block/CU occupancy.
// Old 128x128 kernel kept for pred (N=1089) and fc (N=128) only.
// ---------------------------------------------------------------------------

typedef unsigned short ushort_t;
typedef short short8 __attribute__((ext_vector_type(8)));
typedef float floatx4 __attribute__((ext_vector_type(4)));

__device__ __forceinline__ unsigned short f2u(float f) {
    union { float f; unsigned u; } x; x.f = f;
    unsigned r = x.u + 0x7fffu + ((x.u >> 16) & 1u);   // round-to-nearest-even
    return (unsigned short)(r >> 16);
}
__device__ __forceinline__ float u2f(unsigned short u) {
    union { unsigned u; float f; } x; x.u = ((unsigned)u) << 16; return x.f;
}

// ---------------------------------------------------------------------------
// Batched weight transpose+convert: src fp32 [K][N] -> dst bf16 [N][Kd]
// (Kd >= K, zero-padded). One launch for all 29 weights.
// ---------------------------------------------------------------------------
struct WJob { const float* src; ushort_t* dst; int K; int N; int Kd; int block0; };
struct WJobs { WJob j[29]; int n; };

__global__ __launch_bounds__(256) void wcvt_k(WJobs jb)
{
    const int bid = blockIdx.x, tid = threadIdx.x;
    int ji = 0;
    for (int t = 1; t < jb.n; ++t) if (jb.j[t].block0 <= bid) ji = t;
    const WJob w = jb.j[ji];
    const int lb = bid - w.block0;
    const int tilesN = (w.N + 31) >> 5;
    const int tk = lb / tilesN, tn = lb - tk * tilesN;
    const int k0 = tk * 32, n0 = tn * 32;
    __shared__ float T[32][33];
    const int c = tid & 31, rr = tid >> 5;
#pragma unroll
    for (int p = 0; p < 4; ++p) {
        int r = rr + p * 8;
        int k = k0 + r, n = n0 + c;
        T[r][c] = (k < w.K && n < w.N) ? w.src[(size_t)k * w.N + n] : 0.f;
    }
    __syncthreads();
#pragma unroll
    for (int p = 0; p < 4; ++p) {
        int r = rr + p * 8;
        int n = n0 + r, k = k0 + c;
        if (n < w.N && k < w.Kd) w.dst[(size_t)n * w.Kd + k] = f2u(T[c][r]);
    }
}

// ---------------------------------------------------------------------------
// Wide-tile MFMA GEMM: C[M,N] = A[M,K] @ B[K,N] (+bias, epilogues), B given
// as Bt[N][K] bf16. BM=64, BN=512, BK=32, 256 threads (4 waves), each wave
// 64x128 via 4x8 of 16x16x32 MFMA. Requires M%64==0, N%512==0, K%32==0.
// A fetched once from HBM (grid.x = N/512). Reg-staged prefetch: the next
// k-tile's global loads are issued before the current tile's MFMA cluster.
// EPI: 0=bias, 1=relu, 2=+res, 4=0.9*res+0.1*sigmoid
// ---------------------------------------------------------------------------
template<int EPI, bool AF32, bool WB, bool WF>
__global__ __launch_bounds__(256) void mfma_gemm_w(
    const void* __restrict__ Av, int lda,
    const ushort_t* __restrict__ Bt, int ldb,
    const float* __restrict__ bias,
    const float* __restrict__ res,
    float* __restrict__ Cf, ushort_t* __restrict__ Cb,
    int M, int N, int K)
{
    __shared__ __align__(16) ushort_t As[64][40];    // stride 80B
    __shared__ __align__(16) ushort_t Bs[512][40];

    const int tid  = threadIdx.x;
    const int lane = tid & 63, wave = tid >> 6;
    const int wc = wave * 128;
    const int lrow = lane & 15, quad = lane >> 4;
    const int row0 = blockIdx.y * 64, col0 = blockIdx.x * 512;

    const int arow = tid >> 2;          // 0..63
    const int ako  = (tid & 3) * 8;     // 0,8,16,24

    floatx4 acc[4][8];
#pragma unroll
    for (int i = 0; i < 4; ++i)
#pragma unroll
        for (int j = 0; j < 8; ++j) acc[i][j] = (floatx4){0.f, 0.f, 0.f, 0.f};

    uint4 ra;        // A stage regs (1 uint4 = 8 bf16 per thread)
    uint4 rb[8];     // B stage regs (8 uint4 per thread)

    auto loadA = [&](int k0) {
        if (AF32) {
            const float* pa = (const float*)Av + (size_t)(row0 + arow) * lda + k0 + ako;
            float4 f0 = *(const float4*)pa;
            float4 f1 = *(const float4*)(pa + 4);
            ra.x = (unsigned)f2u(f0.x) | ((unsigned)f2u(f0.y) << 16);
            ra.y = (unsigned)f2u(f0.z) | ((unsigned)f2u(f0.w) << 16);
            ra.z = (unsigned)f2u(f1.x) | ((unsigned)f2u(f1.y) << 16);
            ra.w = (unsigned)f2u(f1.z) | ((unsigned)f2u(f1.w) << 16);
        } else {
            ra = *(const uint4*)((const ushort_t*)Av + (size_t)(row0 + arow) * lda + k0 + ako);
        }
    };
    auto loadB = [&](int k0) {
#pragma unroll
        for (int p = 0; p < 8; ++p) {
            const int idx = p * 256 + tid;
            const int n = idx >> 2, ko = (idx & 3) * 8;
            rb[p] = *(const uint4*)(Bt + (size_t)(col0 + n) * ldb + k0 + ko);
        }
    };
    auto writeLDS = [&]() {
        *(uint4*)&As[arow][ako] = ra;
#pragma unroll
        for (int p = 0; p < 8; ++p) {
            const int idx = p * 256 + tid;
            const int n = idx >> 2, ko = (idx & 3) * 8;
            *(uint4*)&Bs[n][ko] = rb[p];
        }
    };

    // prologue: stage k-tile 0
    loadA(0); loadB(0);
    writeLDS();
    __syncthreads();

    for (int k0 = 0; k0 < K; k0 += 32) {
        const int kn = k0 + 32;
        const bool more = (kn < K);
        if (more) { loadA(kn); loadB(kn); }   // issue next tile's loads early

        short8 af[4], bf[8];
#pragma unroll
        for (int i = 0; i < 4; ++i)
            af[i] = *(const short8*)&As[i * 16 + lrow][quad * 8];
#pragma unroll
        for (int j = 0; j < 8; ++j)
            bf[j] = *(const short8*)&Bs[wc + j * 16 + lrow][quad * 8];
#pragma unroll
        for (int i = 0; i < 4; ++i)
#pragma unroll
            for (int j = 0; j < 8; ++j)
                acc[i][j] = __builtin_amdgcn_mfma_f32_16x16x32_bf16(af[i], bf[j], acc[i][j], 0, 0, 0);

        __syncthreads();
        if (more) { writeLDS(); __syncthreads(); }
    }

    // ---- epilogue
#pragma unroll
    for (int j = 0; j < 8; ++j) {
        const int col = col0 + wc + j * 16 + lrow;
        if (col >= N) continue;
        const float bv = bias[col];
#pragma unroll
        for (int i = 0; i < 4; ++i) {
#pragma unroll
            for (int r = 0; r < 4; ++r) {
                const int row = row0 + i * 16 + quad * 4 + r;
                const size_t off = (size_t)row * N + col;
                float v = acc[i][j][r] + bv;
                if (EPI == 1) v = fmaxf(v, 0.f);
                if (EPI == 2) v += res[off];
                if (EPI == 4) v = 0.9f * res[off] + 0.1f * (1.f / (1.f + __expf(-v)));
                if (WF) Cf[off] = v;
                if (WB) Cb[off] = f2u(v);
            }
        }
    }
}

// ---------------------------------------------------------------------------
// Legacy 128x128 MFMA GEMM (kept for pred N=1089 and fc N=128).
// Requires M%128==0, K%64==0.
// ---------------------------------------------------------------------------
template<int EPI, bool AF32, bool WB, bool WF>
__global__ __launch_bounds__(256) void mfma_gemm(
    const void* __restrict__ Av, int lda,
    const ushort_t* __restrict__ Bt, int ldb,
    const float* __restrict__ bias,
    const float* __restrict__ res,
    float* __restrict__ Cf, ushort_t* __restrict__ Cb,
    int M, int N, int K)
{
    __shared__ __align__(16) ushort_t As[128][72];
    __shared__ __align__(16) ushort_t Bs[128][72];

    const int tid  = threadIdx.x;
    const int lane = tid & 63, wave = tid >> 6;
    const int wr = (wave >> 1) * 64, wc = (wave & 1) * 64;
    const int lrow = lane & 15, quad = lane >> 4;
    const int row0 = blockIdx.y * 128, col0 = blockIdx.x * 128;

    const int srow  = tid >> 3;         // 0..31
    const int skoff = (tid & 7) * 8;    // 0..56

    floatx4 acc[4][4];
#pragma unroll
    for (int i = 0; i < 4; ++i)
#pragma unroll
        for (int j = 0; j < 4; ++j) acc[i][j] = (floatx4){0.f, 0.f, 0.f, 0.f};

    for (int k0 = 0; k0 < K; k0 += 64) {
#pragma unroll
        for (int p = 0; p < 4; ++p) {
            const int r = p * 32 + srow;
            uint4 val;
            if (AF32) {
                const float* pa = (const float*)Av + (size_t)(row0 + r) * lda + k0 + skoff;
                float4 f0 = *(const float4*)pa;
                float4 f1 = *(const float4*)(pa + 4);
                val.x = (unsigned)f2u(f0.x) | ((unsigned)f2u(f0.y) << 16);
                val.y = (unsigned)f2u(f0.z) | ((unsigned)f2u(f0.w) << 16);
                val.z = (unsigned)f2u(f1.x) | ((unsigned)f2u(f1.y) << 16);
                val.w = (unsigned)f2u(f1.z) | ((unsigned)f2u(f1.w) << 16);
            } else {
                val = *(const uint4*)((const ushort_t*)Av + (size_t)(row0 + r) * lda + k0 + skoff);
            }
            *(uint4*)&As[r][skoff] = val;
        }
#pragma unroll
        for (int p = 0; p < 4; ++p) {
            const int r = p * 32 + srow;
            const int n = col0 + r;
            uint4 val = make_uint4(0u, 0u, 0u, 0u);
            if (n < N) val = *(const uint4*)(Bt + (size_t)n * ldb + k0 + skoff);
            *(uint4*)&Bs[r][skoff] = val;
        }
        __syncthreads();

#pragma unroll
        for (int kk = 0; kk < 2; ++kk) {
            short8 af[4], bfr[4];
#pragma unroll
            for (int i = 0; i < 4; ++i)
                af[i] = *(const short8*)&As[wr + i * 16 + lrow][kk * 32 + quad * 8];
#pragma unroll
            for (int j = 0; j < 4; ++j)
                bfr[j] = *(const short8*)&Bs[wc + j * 16 + lrow][kk * 32 + quad * 8];
#pragma unroll
            for (int i = 0; i < 4; ++i)
#pragma unroll
                for (int j = 0; j < 4; ++j)
                    acc[i][j] = __builtin_amdgcn_mfma_f32_16x16x32_bf16(af[i], bfr[j], acc[i][j], 0, 0, 0);
        }
        __syncthreads();
    }

#pragma unroll
    for (int j = 0; j < 4; ++j) {
        const int col = col0 + wc + j * 16 + lrow;
        if (col >= N) continue;
        const float bv = bias[col];
#pragma unroll
        for (int i = 0; i < 4; ++i) {
#pragma unroll
            for (int r = 0; r < 4; ++r) {
                const int row = row0 + wr + i * 16 + quad * 4 + r;
                const size_t off = (size_t)row * N + col;
                float v = acc[i][j][r] + bv;
                if (EPI == 1) v = fmaxf(v, 0.f);
                if (EPI == 2) v += res[off];
                if (EPI == 4) v = 0.9f * res[off] + 0.1f * (1.f / (1.f + __expf(-v)));
                if (WF) Cf[off] = v;
                if (WB) Cb[off] = f2u(v);
            }
        }
    }
}

// ---------------------------------------------------------------------------
// LayerNorm: fp32 in, bf16 out. std = sqrt(sumsq/511); eps added to std.
// ---------------------------------------------------------------------------
__global__ __launch_bounds__(256) void ln_k(
    const float* __restrict__ x, const float* __restrict__ g,
    const float* __restrict__ b, ushort_t* __restrict__ out)
{
    const int row = blockIdx.x;
    const int tid = threadIdx.x;
    const float* xr = x + (size_t)row * 512;
    float v0 = xr[tid], v1 = xr[tid + 256];

    __shared__ float red[4];
    float s = v0 + v1;
#pragma unroll
    for (int off = 32; off >= 1; off >>= 1) s += __shfl_down(s, off);
    if ((tid & 63) == 0) red[tid >> 6] = s;
    __syncthreads();
    const float mean = (red[0] + red[1] + red[2] + red[3]) * (1.f / 512.f);
    const float d0 = v0 - mean, d1 = v1 - mean;
    __syncthreads();

    float ss = d0 * d0 + d1 * d1;
#pragma unroll
    for (int off = 32; off >= 1; off >>= 1) ss += __shfl_down(ss, off);
    if ((tid & 63) == 0) red[tid >> 6] = ss;
    __syncthreads();
    const float var = (red[0] + red[1] + red[2] + red[3]) * (1.f / 511.f);
    const float inv = 1.f / (sqrtf(var) + 1e-6f);

    ushort_t* orow = out + (size_t)row * 512;
    orow[tid]       = f2u(g[tid]       * (d0 * inv) + b[tid]);
    orow[tid + 256] = f2u(g[tid + 256] * (d1 * inv) + b[tid + 256]);
}

// ---------------------------------------------------------------------------
// Cross-attention (q:33 tok, k/v:24 tok). bf16 in/out, fp32 compute.
// ---------------------------------------------------------------------------
__global__ __launch_bounds__(256) void cross_attn_k(
    const ushort_t* __restrict__ q, const ushort_t* __restrict__ k,
    const ushort_t* __restrict__ v, ushort_t* __restrict__ out)
{
    const int h = blockIdx.x, b = blockIdx.y, tid = threadIdx.x;
    __shared__ float Lq[33 * 64], Lk[24 * 64], Lv[24 * 64], Ls[33 * 24];
    const size_t qoff = ((size_t)b * 33) * 512 + h * 64;
    const size_t koff = ((size_t)b * 24) * 512 + h * 64;

    for (int i = tid; i < 33 * 64; i += 256) {
        int t = i >> 6, d = i & 63;
        Lq[i] = u2f(q[qoff + (size_t)t * 512 + d]);
    }
    for (int i = tid; i < 24 * 64; i += 256) {
        int t = i >> 6, d = i & 63;
        Lk[i] = u2f(k[koff + (size_t)t * 512 + d]);
        Lv[i] = u2f(v[koff + (size_t)t * 512 + d]);
    }
    __syncthreads();

    for (int i = tid; i < 33 * 24; i += 256) {
        int r = i / 24, c = i % 24;
        float s = 0.f;
#pragma unroll
        for (int d = 0; d < 64; ++d) s = fmaf(Lq[r * 64 + d], Lk[c * 64 + d], s);
        Ls[i] = s * 0.125f;
    }
    __syncthreads();

    if (tid < 33) {
        float mx = -1e30f;
        for (int c = 0; c < 24; ++c) mx = fmaxf(mx, Ls[tid * 24 + c]);
        float sum = 0.f;
        for (int c = 0; c < 24; ++c) { float e = __expf(Ls[tid * 24 + c] - mx); Ls[tid * 24 + c] = e; sum += e; }
        float inv = 1.f / sum;
        for (int c = 0; c < 24; ++c) Ls[tid * 24 + c] *= inv;
    }
    __syncthreads();

    for (int i = tid; i < 33 * 64; i += 256) {
        int r = i >> 6, d = i & 63;
        float a = 0.f;
#pragma unroll
        for (int c = 0; c < 24; ++c) a = fmaf(Ls[r * 24 + c], Lv[c * 64 + d], a);
        out[qoff + (size_t)r * 512 + d] = f2u(a);
    }
}

// ---------------------------------------------------------------------------
// Masked self-attention (33 tok), adj fp32, know=True semantics.
// ---------------------------------------------------------------------------
__global__ __launch_bounds__(256) void self_attn_k(
    const ushort_t* __restrict__ q, const ushort_t* __restrict__ k,
    const ushort_t* __restrict__ v, const float* __restrict__ adj,
    ushort_t* __restrict__ out)
{
    const int h = blockIdx.x, b = blockIdx.y, tid = threadIdx.x;
    __shared__ float Lq[33 * 64], Lk[33 * 64], Lv[33 * 64], Ls[33 * 34], Lm[33 * 33];
    const size_t off = ((size_t)b * 33) * 512 + h * 64;

    for (int i = tid; i < 33 * 64; i += 256) {
        int t = i >> 6, d = i & 63;
        Lq[i] = u2f(q[off + (size_t)t * 512 + d]);
        Lk[i] = u2f(k[off + (size_t)t * 512 + d]);
        Lv[i] = u2f(v[off + (size_t)t * 512 + d]);
    }
    for (int i = tid; i < 1089; i += 256) Lm[i] = adj[(size_t)b * 1089 + i];
    __syncthreads();

    for (int i = tid; i < 1089; i += 256) {
        int r = i / 33, c = i % 33;
        float s = 0.f;
#pragma unroll
        for (int d = 0; d < 64; ++d) s = fmaf(Lq[r * 64 + d], Lk[c * 64 + d], s);
        s *= 0.125f;
        float m = Lm[i];
        s = (m == 0.f) ? -1e9f : s * m;
        Ls[r * 34 + c] = s;
    }
    __syncthreads();

    if (tid < 33) {
        float mx = -1e30f;
        for (int c = 0; c < 33; ++c) mx = fmaxf(mx, Ls[tid * 34 + c]);
        float sum = 0.f;
        for (int c = 0; c < 33; ++c) { float e = __expf(Ls[tid * 34 + c] - mx); Ls[tid * 34 + c] = e; sum += e; }
        float inv = 1.f / sum;
        for (int c = 0; c < 33; ++c) Ls[tid * 34 + c] *= inv;
    }
    __syncthreads();

    for (int i = tid; i < 33 * 64; i += 256) {
        int r = i >> 6, d = i & 63;
        float a = 0.f;
#pragma unroll
        for (int c = 0; c < 33; ++c) a = fmaf(Ls[r * 34 + c], Lv[c * 64 + d], a);
        out[off + (size_t)r * 512 + d] = f2u(a);
    }
}

// ---------------------------------------------------------------------------
// rel[b,i,j] = er[b,i,:].er[b,j,:]. bf16 in, bf16 out padded to K=1152.
// ---------------------------------------------------------------------------
__global__ __launch_bounds__(256) void rel_k(
    const ushort_t* __restrict__ er, ushort_t* __restrict__ rel)
{
    const int b = blockIdx.x, tid = threadIdx.x;
    __shared__ float E[33 * 256];
    const ushort_t* src = er + (size_t)b * 33 * 512;

    float accv[5] = {0.f, 0.f, 0.f, 0.f, 0.f};
    for (int half = 0; half < 2; ++half) {
        for (int i = tid; i < 33 * 256; i += 256) {
            int t = i >> 8, d = i & 255;
            E[i] = u2f(src[(size_t)t * 512 + half * 256 + d]);
        }
        __syncthreads();
        for (int u = 0; u < 5; ++u) {
            int i = tid + 256 * u;
            if (i < 1089) {
                int r = i / 33, c = i % 33;
                const float* pr = &E[r * 256];
                const float* pc = &E[c * 256];
                float a = accv[u];
                for (int d = 0; d < 256; d += 4) {
                    float4 x = *(const float4*)&pr[d];
                    float4 y = *(const float4*)&pc[d];
                    a = fmaf(x.x, y.x, fmaf(x.y, y.y, fmaf(x.z, y.z, fmaf(x.w, y.w, a))));
                }
                accv[u] = a;
            }
        }
        __syncthreads();
    }
    for (int u = 0; u < 5; ++u) {
        int i = tid + 256 * u;
        if (i < 1089) rel[(size_t)b * 1152 + i] = f2u(accv[u]);
    }
    for (int i = 1089 + tid; i < 1152; i += 256) rel[(size_t)b * 1152 + i] = 0;
}

// ---------------------------------------------------------------------------
// Classifier head: bf16 cin (512 x 4224), fp32 W (4224 x 32) + sigmoid.
// ---------------------------------------------------------------------------
__global__ __launch_bounds__(256) void cls_k(
    const ushort_t* __restrict__ cin, const float* __restrict__ W,
    const float* __restrict__ bias, float* __restrict__ out)
{
    const int b = blockIdx.x, tid = threadIdx.x;
    const int n = tid & 31, kg = tid >> 5;
    const ushort_t* x = cin + (size_t)b * 4224;
    float acc = 0.f;
    for (int k = kg; k < 4224; k += 8)
        acc = fmaf(u2f(x[k]), W[(size_t)k * 32 + n], acc);

    __shared__ float part[8][32];
    part[kg][n] = acc;
    __syncthreads();
    if (tid < 32) {
        float s = bias[tid];
#pragma unroll
        for (int g = 0; g < 8; ++g) s += part[g][tid];
        out[(size_t)b * 32 + tid] = 1.f / (1.f + __expf(-s));
    }
}

// ---------------------------------------------------------------------------
// Host orchestration
// ---------------------------------------------------------------------------
extern "C" void kernel_launch(void* const* d_in, const int* in_sizes, int n_in,
                              void* d_out, int out_size, void* d_ws, size_t ws_size,
                              hipStream_t stream)
{
    const float* visual   = (const float*)d_in[0];
    const float* entity   = (const float*)d_in[1];
    const float* graph    = (const float*)d_in[2];
    const float* vis_W    = (const float*)d_in[3];
    const float* vis_b    = (const float*)d_in[4];
    const float* ent_W    = (const float*)d_in[5];
    const float* ent_b    = (const float*)d_in[6];
    const float* ca_Wq    = (const float*)d_in[7];
    const float* ca_bq    = (const float*)d_in[8];
    const float* ca_Wk    = (const float*)d_in[9];
    const float* ca_bk    = (const float*)d_in[10];
    const float* ca_Wv    = (const float*)d_in[11];
    const float* ca_bv    = (const float*)d_in[12];
    const float* ca_Wo    = (const float*)d_in[13];
    const float* ca_bo    = (const float*)d_in[14];
    const float* kp_W     = (const float*)d_in[15];
    const float* kp_b     = (const float*)d_in[16];
    const float* pred_W   = (const float*)d_in[17];
    const float* pred_b   = (const float*)d_in[18];
    const float* l_Wq     = (const float*)d_in[19];
    const float* l_bq     = (const float*)d_in[20];
    const float* l_Wk     = (const float*)d_in[21];
    const float* l_bk     = (const float*)d_in[22];
    const float* l_Wv     = (const float*)d_in[23];
    const float* l_bv     = (const float*)d_in[24];
    const float* l_Wo     = (const float*)d_in[25];
    const float* l_bo     = (const float*)d_in[26];
    const float* l_ffW1   = (const float*)d_in[27];
    const float* l_ffb1   = (const float*)d_in[28];
    const float* l_ffW2   = (const float*)d_in[29];
    const float* l_ffb2   = (const float*)d_in[30];
    const float* l_n1_g   = (const float*)d_in[31];
    const float* l_n1_b   = (const float*)d_in[32];
    const float* l_n2_g   = (const float*)d_in[33];
    const float* l_n2_b   = (const float*)d_in[34];
    const float* fin_g    = (const float*)d_in[35];
    const float* fin_b    = (const float*)d_in[36];
    const float* ad_W1    = (const float*)d_in[37];
    const float* ad_b1    = (const float*)d_in[38];
    const float* ad_W2    = (const float*)d_in[39];
    const float* ad_b2    = (const float*)d_in[40];
    const float* sc_fc_W  = (const float*)d_in[41];
    const float* sc_fc_b  = (const float*)d_in[42];
    const float* sc_cls_W = (const float*)d_in[43];
    const float* sc_cls_b = (const float*)d_in[44];

    const int B  = 512;
    const int Mv = B * 24;   // 12288
    const int Me = B * 33;   // 16896

    // ---- workspace layout
    char* wsb = (char*)d_ws;
    size_t off = 0;
    auto alloc_us = [&](size_t elems) -> ushort_t* {
        ushort_t* p = (ushort_t*)(wsb + off); off += ((elems * 2 + 255) & ~(size_t)255); return p; };
    auto alloc_f = [&](size_t elems) -> float* {
        float* p = (float*)(wsb + off); off += ((elems * 4 + 255) & ~(size_t)255); return p; };

    // weight (bf16, transposed) region
    ushort_t* vis_Wt = alloc_us((size_t)512 * 2048);
    ushort_t* ent_Wt = alloc_us((size_t)512 * 4096);
    ushort_t* caq_t  = alloc_us((size_t)512 * 512);
    ushort_t* cak_t  = alloc_us((size_t)512 * 512);
    ushort_t* cav_t  = alloc_us((size_t)512 * 512);
    ushort_t* cao_t  = alloc_us((size_t)512 * 512);
    ushort_t* kp_t   = alloc_us((size_t)512 * 512);
    ushort_t* pred_t = alloc_us((size_t)1089 * 1152);
    ushort_t* lw_t   = alloc_us((size_t)18 * 512 * 512);   // [layer*6 + slot]
    ushort_t* ad1_t  = alloc_us((size_t)512 * 512);
    ushort_t* ad2_t  = alloc_us((size_t)4096 * 512);
    ushort_t* fc_t   = alloc_us((size_t)128 * 512);

    // fp32 buffers
    float* o_x   = alloc_f((size_t)Me * 512);
    float* o_adj = alloc_f((size_t)B * 1089);

    // bf16 activation buffers
    ushort_t* o_xb  = alloc_us((size_t)Me * 512);
    ushort_t* o_xn  = alloc_us((size_t)Me * 512);
    ushort_t* o_q   = alloc_us((size_t)Me * 512);
    ushort_t* o_k   = alloc_us((size_t)Me * 512);
    ushort_t* o_vv  = alloc_us((size_t)Me * 512);
    ushort_t* o_v   = alloc_us((size_t)Mv * 512);
    ushort_t* o_rel = alloc_us((size_t)B * 1152);
    ushort_t* o_cls = alloc_us((size_t)Me * 128);

    float* out_adapted = (float*)d_out;
    float* out_cls     = out_adapted + (size_t)Me * 4096;

    // ---- weight conversion jobs
    WJobs J; int nb = 0, ji = 0;
    auto addjob = [&](const float* src, ushort_t* dst, int K, int N, int Kd) {
        J.j[ji].src = src; J.j[ji].dst = dst; J.j[ji].K = K; J.j[ji].N = N;
        J.j[ji].Kd = Kd; J.j[ji].block0 = nb;
        nb += ((Kd + 31) / 32) * ((N + 31) / 32);
        ++ji;
    };
    addjob(vis_W, vis_Wt, 2048, 512, 2048);
    addjob(ent_W, ent_Wt, 4096, 512, 4096);
    addjob(ca_Wq, caq_t, 512, 512, 512);
    addjob(ca_Wk, cak_t, 512, 512, 512);
    addjob(ca_Wv, cav_t, 512, 512, 512);
    addjob(ca_Wo, cao_t, 512, 512, 512);
    addjob(kp_W,  kp_t,  512, 512, 512);
    addjob(pred_W, pred_t, 1089, 1089, 1152);
    for (int i = 0; i < 3; ++i) {
        addjob(l_Wq   + (size_t)i * 262144, lw_t + (size_t)(i * 6 + 0) * 262144, 512, 512, 512);
        addjob(l_Wk   + (size_t)i * 262144, lw_t + (size_t)(i * 6 + 1) * 262144, 512, 512, 512);
        addjob(l_Wv   + (size_t)i * 262144, lw_t + (size_t)(i * 6 + 2) * 262144, 512, 512, 512);
        addjob(l_Wo   + (size_t)i * 262144, lw_t + (size_t)(i * 6 + 3) * 262144, 512, 512, 512);
        addjob(l_ffW1 + (size_t)i * 262144, lw_t + (size_t)(i * 6 + 4) * 262144, 512, 512, 512);
        addjob(l_ffW2 + (size_t)i * 262144, lw_t + (size_t)(i * 6 + 5) * 262144, 512, 512, 512);
    }
    addjob(ad_W1, ad1_t, 512, 512, 512);
    addjob(ad_W2, ad2_t, 512, 4096, 512);
    addjob(sc_fc_W, fc_t, 512, 128, 512);
    J.n = ji;

    dim3 blk(256);
    wcvt_k<<<dim3(nb), blk, 0, stream>>>(J);

    auto g2  = [](int M, int N) { return dim3((unsigned)((N + 127) / 128), (unsigned)(M / 128)); };
    auto g2w = [](int M, int N) { return dim3((unsigned)(N / 512), (unsigned)(M / 64)); };
    dim3 attn_grid(8, B);

    // ---- input projections (fp32 A, converted in staging)
    mfma_gemm_w<0, true, true, false><<<g2w(Mv, 512), blk, 0, stream>>>(
        visual, 2048, vis_Wt, 2048, vis_b, nullptr, nullptr, o_v, Mv, 512, 2048);
    mfma_gemm_w<0, true, true, false><<<g2w(Me, 512), blk, 0, stream>>>(
        entity, 4096, ent_Wt, 4096, ent_b, nullptr, nullptr, o_xn, Me, 512, 4096);   // e -> o_xn

    // ---- cross attention
    mfma_gemm_w<0, false, true, false><<<g2w(Me, 512), blk, 0, stream>>>(
        o_xn, 512, caq_t, 512, ca_bq, nullptr, nullptr, o_q, Me, 512, 512);
    mfma_gemm_w<0, false, true, false><<<g2w(Mv, 512), blk, 0, stream>>>(
        o_v, 512, cak_t, 512, ca_bk, nullptr, nullptr, o_k, Mv, 512, 512);
    mfma_gemm_w<0, false, true, false><<<g2w(Mv, 512), blk, 0, stream>>>(
        o_v, 512, cav_t, 512, ca_bv, nullptr, nullptr, o_vv, Mv, 512, 512);
    cross_attn_k<<<attn_grid, blk, 0, stream>>>(o_q, o_k, o_vv, o_xn);   // attc -> o_xn
    mfma_gemm_w<0, false, true, true><<<g2w(Me, 512), blk, 0, stream>>>(
        o_xn, 512, cao_t, 512, ca_bo, nullptr, o_x, o_xb, Me, 512, 512); // ef -> x (f32+bf16)

    // ---- knowledge path
    mfma_gemm_w<0, false, true, false><<<g2w(Me, 512), blk, 0, stream>>>(
        o_xb, 512, kp_t, 512, kp_b, nullptr, nullptr, o_q, Me, 512, 512);            // er
    rel_k<<<dim3(B), blk, 0, stream>>>(o_q, o_rel);
    mfma_gemm<4, false, false, true><<<g2(512, 1089), blk, 0, stream>>>(
        o_rel, 1152, pred_t, 1152, pred_b, graph, o_adj, nullptr, 512, 1089, 1152);  // adj

    // ---- 3 transformer layers
    for (int i = 0; i < 3; ++i) {
        const ushort_t* Wq = lw_t + (size_t)(i * 6 + 0) * 262144;
        const ushort_t* Wk = lw_t + (size_t)(i * 6 + 1) * 262144;
        const ushort_t* Wv = lw_t + (size_t)(i * 6 + 2) * 262144;
        const ushort_t* Wo = lw_t + (size_t)(i * 6 + 3) * 262144;
        const ushort_t* W1 = lw_t + (size_t)(i * 6 + 4) * 262144;
        const ushort_t* W2 = lw_t + (size_t)(i * 6 + 5) * 262144;

        ln_k<<<dim3(Me), blk, 0, stream>>>(o_x, l_n1_g + (size_t)i * 512, l_n1_b + (size_t)i * 512, o_xn);
        mfma_gemm_w<0, false, true, false><<<g2w(Me, 512), blk, 0, stream>>>(
            o_xn, 512, Wq, 512, l_bq + (size_t)i * 512, nullptr, nullptr, o_q, Me, 512, 512);
        mfma_gemm_w<0, false, true, false><<<g2w(Me, 512), blk, 0, stream>>>(
            o_xb, 512, Wk, 512, l_bk + (size_t)i * 512, nullptr, nullptr, o_k, Me, 512, 512);
        mfma_gemm_w<0, false, true, false><<<g2w(Me, 512), blk, 0, stream>>>(
            o_xb, 512, Wv, 512, l_bv + (size_t)i * 512, nullptr, nullptr, o_vv, Me, 512, 512);
        self_attn_k<<<attn_grid, blk, 0, stream>>>(o_q, o_k, o_vv, o_adj, o_xn);
        mfma_gemm_w<2, false, true, true><<<g2w(Me, 512), blk, 0, stream>>>(
            o_xn, 512, Wo, 512, l_bo + (size_t)i * 512, o_x, o_x, o_xb, Me, 512, 512);   // x += att
        ln_k<<<dim3(Me), blk, 0, stream>>>(o_x, l_n2_g + (size_t)i * 512, l_n2_b + (size_t)i * 512, o_xn);
        mfma_gemm_w<1, false, true, false><<<g2w(Me, 512), blk, 0, stream>>>(
            o_xn, 512, W1, 512, l_ffb1 + (size_t)i * 512, nullptr, nullptr, o_q, Me, 512, 512); // relu
        mfma_gemm_w<2, false, true, true><<<g2w(Me, 512), blk, 0, stream>>>(
            o_q, 512, W2, 512, l_ffb2 + (size_t)i * 512, o_x, o_x, o_xb, Me, 512, 512);  // x += ff
    }

    // ---- final LN + heads
    ln_k<<<dim3(Me), blk, 0, stream>>>(o_x, fin_g, fin_b, o_xn);   // emb
    mfma_gemm_w<0, false, true, false><<<g2w(Me, 512), blk, 0, stream>>>(
        o_xn, 512, ad1_t, 512, ad_b1, nullptr, nullptr, o_q, Me, 512, 512);
    mfma_gemm_w<0, false, false, true><<<g2w(Me, 4096), blk, 0, stream>>>(
        o_q, 512, ad2_t, 512, ad_b2, nullptr, out_adapted, nullptr, Me, 4096, 512);
    mfma_gemm<0, false, true, false><<<g2(Me, 128), blk, 0, stream>>>(
        o_xn, 512, fc_t, 512, sc_fc_b, nullptr, nullptr, o_cls, Me, 128, 512);
    cls_k<<<dim3(B), blk, 0, stream>>>(o_cls, sc_cls_W, sc_cls_b, out_cls);
}

// Round 2
// 3409.904 us; speedup vs baseline: 1.7217x; 1.7217x over previous
//
#include <hip/hip_runtime.h>
#include <hip/hip_bf16.h>
#include <math.h>

// ---------------------------------------------------------------------------
// R4: revert to the proven R2 128x128 GEMM structure (R3 wide-tile was
// latency-bound at 1 block/CU: Occupancy 6.3%, MfmaUtil 3.2%).
// New vs R2:
//  (1) visual/entity pre-converted to bf16 (f2b_k) so the big input
//      projections read half the bytes and the 4x col-panel A re-read is
//      L3-absorbable. Runtime ws_size guard; falls back to fp32-A path.
//  (2) K+V projections fused into one N=1024 GEMM (weights adjacent in the
//      converted layout); dual-bias epilogue; attention reads KV stride 1024.
//      Grid 528->1056 blocks (better fill), 8 launches -> 4.
// ---------------------------------------------------------------------------

typedef unsigned short ushort_t;
typedef short short8 __attribute__((ext_vector_type(8)));
typedef float floatx4 __attribute__((ext_vector_type(4)));

__device__ __forceinline__ unsigned short f2u(float f) {
    union { float f; unsigned u; } x; x.f = f;
    unsigned r = x.u + 0x7fffu + ((x.u >> 16) & 1u);   // round-to-nearest-even
    return (unsigned short)(r >> 16);
}
__device__ __forceinline__ float u2f(unsigned short u) {
    union { unsigned u; float f; } x; x.u = ((unsigned)u) << 16; return x.f;
}

// ---------------------------------------------------------------------------
// Batched weight transpose+convert: src fp32 [K][N] -> dst bf16 [N][Kd]
// ---------------------------------------------------------------------------
struct WJob { const float* src; ushort_t* dst; int K; int N; int Kd; int block0; };
struct WJobs { WJob j[29]; int n; };

__global__ __launch_bounds__(256) void wcvt_k(WJobs jb)
{
    const int bid = blockIdx.x, tid = threadIdx.x;
    int ji = 0;
    for (int t = 1; t < jb.n; ++t) if (jb.j[t].block0 <= bid) ji = t;
    const WJob w = jb.j[ji];
    const int lb = bid - w.block0;
    const int tilesN = (w.N + 31) >> 5;
    const int tk = lb / tilesN, tn = lb - tk * tilesN;
    const int k0 = tk * 32, n0 = tn * 32;
    __shared__ float T[32][33];
    const int c = tid & 31, rr = tid >> 5;
#pragma unroll
    for (int p = 0; p < 4; ++p) {
        int r = rr + p * 8;
        int k = k0 + r, n = n0 + c;
        T[r][c] = (k < w.K && n < w.N) ? w.src[(size_t)k * w.N + n] : 0.f;
    }
    __syncthreads();
#pragma unroll
    for (int p = 0; p < 4; ++p) {
        int r = rr + p * 8;
        int n = n0 + r, k = k0 + c;
        if (n < w.N && k < w.Kd) w.dst[(size_t)n * w.Kd + k] = f2u(T[c][r]);
    }
}

// ---------------------------------------------------------------------------
// fp32 -> bf16 bulk convert (vectorized, grid-stride). n8 = elems/8.
// ---------------------------------------------------------------------------
__global__ __launch_bounds__(256) void f2b_k(
    const float* __restrict__ src, ushort_t* __restrict__ dst, unsigned n8)
{
    unsigned i = blockIdx.x * 256 + threadIdx.x;
    const unsigned stride = gridDim.x * 256;
    for (; i < n8; i += stride) {
        const size_t o = (size_t)i * 8;
        float4 a = *(const float4*)(src + o);
        float4 b = *(const float4*)(src + o + 4);
        uint4 v;
        v.x = (unsigned)f2u(a.x) | ((unsigned)f2u(a.y) << 16);
        v.y = (unsigned)f2u(a.z) | ((unsigned)f2u(a.w) << 16);
        v.z = (unsigned)f2u(b.x) | ((unsigned)f2u(b.y) << 16);
        v.w = (unsigned)f2u(b.z) | ((unsigned)f2u(b.w) << 16);
        *(uint4*)(dst + o) = v;
    }
}

// ---------------------------------------------------------------------------
// MFMA GEMM: C[M,N] = A[M,K] @ B[K,N] (+bias, epilogues), B given as
// Bt[N][K] bf16. 128x128 tile, BK=64, 4 waves, each wave 64x64 via 4x4 of
// 16x16x32 MFMA. Requires M%128==0, K%64==0.
// EPI: 0=bias, 1=relu, 2=+res, 4=0.9*res+0.1*sigmoid
// B2: dual bias, split at col 512 (fused K|V or similar concat GEMMs).
// ---------------------------------------------------------------------------
template<int EPI, bool AF32, bool WB, bool WF, bool B2>
__global__ __launch_bounds__(256) void mfma_gemm(
    const void* __restrict__ Av, int lda,
    const ushort_t* __restrict__ Bt, int ldb,
    const float* __restrict__ bias,
    const float* __restrict__ bias2,
    const float* __restrict__ res,
    float* __restrict__ Cf, ushort_t* __restrict__ Cb,
    int M, int N, int K)
{
    __shared__ __align__(16) ushort_t As[128][72];   // stride 144B: uniform banks
    __shared__ __align__(16) ushort_t Bs[128][72];

    const int tid  = threadIdx.x;
    const int lane = tid & 63, wave = tid >> 6;
    const int wr = (wave >> 1) * 64, wc = (wave & 1) * 64;
    const int lrow = lane & 15, quad = lane >> 4;
    const int row0 = blockIdx.y * 128, col0 = blockIdx.x * 128;

    const int srow  = tid >> 3;         // 0..31
    const int skoff = (tid & 7) * 8;    // 0..56 (bf16 elements)

    floatx4 acc[4][4];
#pragma unroll
    for (int i = 0; i < 4; ++i)
#pragma unroll
        for (int j = 0; j < 4; ++j) acc[i][j] = (floatx4){0.f, 0.f, 0.f, 0.f};

    for (int k0 = 0; k0 < K; k0 += 64) {
        // ---- stage A (128 x 64 bf16)
#pragma unroll
        for (int p = 0; p < 4; ++p) {
            const int r = p * 32 + srow;
            uint4 val;
            if (AF32) {
                const float* pa = (const float*)Av + (size_t)(row0 + r) * lda + k0 + skoff;
                float4 f0 = *(const float4*)pa;
                float4 f1 = *(const float4*)(pa + 4);
                val.x = (unsigned)f2u(f0.x) | ((unsigned)f2u(f0.y) << 16);
                val.y = (unsigned)f2u(f0.z) | ((unsigned)f2u(f0.w) << 16);
                val.z = (unsigned)f2u(f1.x) | ((unsigned)f2u(f1.y) << 16);
                val.w = (unsigned)f2u(f1.z) | ((unsigned)f2u(f1.w) << 16);
            } else {
                val = *(const uint4*)((const ushort_t*)Av + (size_t)(row0 + r) * lda + k0 + skoff);
            }
            *(uint4*)&As[r][skoff] = val;
        }
        // ---- stage B (128 cols x 64 bf16 from Bt[N][K]); zero OOB cols
#pragma unroll
        for (int p = 0; p < 4; ++p) {
            const int r = p * 32 + srow;
            const int n = col0 + r;
            uint4 val = make_uint4(0u, 0u, 0u, 0u);
            if (n < N) val = *(const uint4*)(Bt + (size_t)n * ldb + k0 + skoff);
            *(uint4*)&Bs[r][skoff] = val;
        }
        __syncthreads();

#pragma unroll
        for (int kk = 0; kk < 2; ++kk) {
            short8 af[4], bfr[4];
#pragma unroll
            for (int i = 0; i < 4; ++i)
                af[i] = *(const short8*)&As[wr + i * 16 + lrow][kk * 32 + quad * 8];
#pragma unroll
            for (int j = 0; j < 4; ++j)
                bfr[j] = *(const short8*)&Bs[wc + j * 16 + lrow][kk * 32 + quad * 8];
#pragma unroll
            for (int i = 0; i < 4; ++i)
#pragma unroll
                for (int j = 0; j < 4; ++j)
                    acc[i][j] = __builtin_amdgcn_mfma_f32_16x16x32_bf16(af[i], bfr[j], acc[i][j], 0, 0, 0);
        }
        __syncthreads();
    }

    // ---- epilogue
#pragma unroll
    for (int j = 0; j < 4; ++j) {
        const int col = col0 + wc + j * 16 + lrow;
        if (col >= N) continue;
        float bv;
        if (B2) bv = (col < 512) ? bias[col] : bias2[col - 512];
        else    bv = bias[col];
#pragma unroll
        for (int i = 0; i < 4; ++i) {
#pragma unroll
            for (int r = 0; r < 4; ++r) {
                const int row = row0 + wr + i * 16 + quad * 4 + r;
                const size_t off = (size_t)row * N + col;
                float v = acc[i][j][r] + bv;
                if (EPI == 1) v = fmaxf(v, 0.f);
                if (EPI == 2) v += res[off];
                if (EPI == 4) v = 0.9f * res[off] + 0.1f * (1.f / (1.f + __expf(-v)));
                if (WF) Cf[off] = v;
                if (WB) Cb[off] = f2u(v);
            }
        }
    }
}

// ---------------------------------------------------------------------------
// LayerNorm: fp32 in, bf16 out. std = sqrt(sumsq/511); eps added to std.
// ---------------------------------------------------------------------------
__global__ __launch_bounds__(256) void ln_k(
    const float* __restrict__ x, const float* __restrict__ g,
    const float* __restrict__ b, ushort_t* __restrict__ out)
{
    const int row = blockIdx.x;
    const int tid = threadIdx.x;
    const float* xr = x + (size_t)row * 512;
    float v0 = xr[tid], v1 = xr[tid + 256];

    __shared__ float red[4];
    float s = v0 + v1;
#pragma unroll
    for (int off = 32; off >= 1; off >>= 1) s += __shfl_down(s, off);
    if ((tid & 63) == 0) red[tid >> 6] = s;
    __syncthreads();
    const float mean = (red[0] + red[1] + red[2] + red[3]) * (1.f / 512.f);
    const float d0 = v0 - mean, d1 = v1 - mean;
    __syncthreads();

    float ss = d0 * d0 + d1 * d1;
#pragma unroll
    for (int off = 32; off >= 1; off >>= 1) ss += __shfl_down(ss, off);
    if ((tid & 63) == 0) red[tid >> 6] = ss;
    __syncthreads();
    const float var = (red[0] + red[1] + red[2] + red[3]) * (1.f / 511.f);
    const float inv = 1.f / (sqrtf(var) + 1e-6f);

    ushort_t* orow = out + (size_t)row * 512;
    orow[tid]       = f2u(g[tid]       * (d0 * inv) + b[tid]);
    orow[tid + 256] = f2u(g[tid + 256] * (d1 * inv) + b[tid + 256]);
}

// ---------------------------------------------------------------------------
// Cross-attention (q:33 tok, k/v:24 tok). q ld 512; kv fused ld 1024
// (k at +0, v at +512). bf16 in/out, fp32 compute.
// ---------------------------------------------------------------------------
__global__ __launch_bounds__(256) void cross_attn_k(
    const ushort_t* __restrict__ q, const ushort_t* __restrict__ kv,
    ushort_t* __restrict__ out)
{
    const int h = blockIdx.x, b = blockIdx.y, tid = threadIdx.x;
    __shared__ float Lq[33 * 64], Lk[24 * 64], Lv[24 * 64], Ls[33 * 24];
    const size_t qoff  = ((size_t)b * 33) * 512 + h * 64;
    const size_t kvoff = ((size_t)b * 24) * 1024 + h * 64;

    for (int i = tid; i < 33 * 64; i += 256) {
        int t = i >> 6, d = i & 63;
        Lq[i] = u2f(q[qoff + (size_t)t * 512 + d]);
    }
    for (int i = tid; i < 24 * 64; i += 256) {
        int t = i >> 6, d = i & 63;
        Lk[i] = u2f(kv[kvoff + (size_t)t * 1024 + d]);
        Lv[i] = u2f(kv[kvoff + (size_t)t * 1024 + 512 + d]);
    }
    __syncthreads();

    for (int i = tid; i < 33 * 24; i += 256) {
        int r = i / 24, c = i % 24;
        float s = 0.f;
#pragma unroll
        for (int d = 0; d < 64; ++d) s = fmaf(Lq[r * 64 + d], Lk[c * 64 + d], s);
        Ls[i] = s * 0.125f;
    }
    __syncthreads();

    if (tid < 33) {
        float mx = -1e30f;
        for (int c = 0; c < 24; ++c) mx = fmaxf(mx, Ls[tid * 24 + c]);
        float sum = 0.f;
        for (int c = 0; c < 24; ++c) { float e = __expf(Ls[tid * 24 + c] - mx); Ls[tid * 24 + c] = e; sum += e; }
        float inv = 1.f / sum;
        for (int c = 0; c < 24; ++c) Ls[tid * 24 + c] *= inv;
    }
    __syncthreads();

    for (int i = tid; i < 33 * 64; i += 256) {
        int r = i >> 6, d = i & 63;
        float a = 0.f;
#pragma unroll
        for (int c = 0; c < 24; ++c) a = fmaf(Ls[r * 24 + c], Lv[c * 64 + d], a);
        out[qoff + (size_t)r * 512 + d] = f2u(a);
    }
}

// ---------------------------------------------------------------------------
// Masked self-attention (33 tok), adj fp32, know=True. q ld 512; kv ld 1024.
// ---------------------------------------------------------------------------
__global__ __launch_bounds__(256) void self_attn_k(
    const ushort_t* __restrict__ q, const ushort_t* __restrict__ kv,
    const float* __restrict__ adj, ushort_t* __restrict__ out)
{
    const int h = blockIdx.x, b = blockIdx.y, tid = threadIdx.x;
    __shared__ float Lq[33 * 64], Lk[33 * 64], Lv[33 * 64], Ls[33 * 34], Lm[33 * 33];
    const size_t off  = ((size_t)b * 33) * 512 + h * 64;
    const size_t kvo  = ((size_t)b * 33) * 1024 + h * 64;

    for (int i = tid; i < 33 * 64; i += 256) {
        int t = i >> 6, d = i & 63;
        Lq[i] = u2f(q[off + (size_t)t * 512 + d]);
        Lk[i] = u2f(kv[kvo + (size_t)t * 1024 + d]);
        Lv[i] = u2f(kv[kvo + (size_t)t * 1024 + 512 + d]);
    }
    for (int i = tid; i < 1089; i += 256) Lm[i] = adj[(size_t)b * 1089 + i];
    __syncthreads();

    for (int i = tid; i < 1089; i += 256) {
        int r = i / 33, c = i % 33;
        float s = 0.f;
#pragma unroll
        for (int d = 0; d < 64; ++d) s = fmaf(Lq[r * 64 + d], Lk[c * 64 + d], s);
        s *= 0.125f;
        float m = Lm[i];
        s = (m == 0.f) ? -1e9f : s * m;
        Ls[r * 34 + c] = s;
    }
    __syncthreads();

    if (tid < 33) {
        float mx = -1e30f;
        for (int c = 0; c < 33; ++c) mx = fmaxf(mx, Ls[tid * 34 + c]);
        float sum = 0.f;
        for (int c = 0; c < 33; ++c) { float e = __expf(Ls[tid * 34 + c] - mx); Ls[tid * 34 + c] = e; sum += e; }
        float inv = 1.f / sum;
        for (int c = 0; c < 33; ++c) Ls[tid * 34 + c] *= inv;
    }
    __syncthreads();

    for (int i = tid; i < 33 * 64; i += 256) {
        int r = i >> 6, d = i & 63;
        float a = 0.f;
#pragma unroll
        for (int c = 0; c < 33; ++c) a = fmaf(Ls[r * 34 + c], Lv[c * 64 + d], a);
        out[off + (size_t)r * 512 + d] = f2u(a);
    }
}

// ---------------------------------------------------------------------------
// rel[b,i,j] = er[b,i,:].er[b,j,:]. bf16 in, bf16 out padded to K=1152.
// ---------------------------------------------------------------------------
__global__ __launch_bounds__(256) void rel_k(
    const ushort_t* __restrict__ er, ushort_t* __restrict__ rel)
{
    const int b = blockIdx.x, tid = threadIdx.x;
    __shared__ float E[33 * 256];
    const ushort_t* src = er + (size_t)b * 33 * 512;

    float accv[5] = {0.f, 0.f, 0.f, 0.f, 0.f};
    for (int half = 0; half < 2; ++half) {
        for (int i = tid; i < 33 * 256; i += 256) {
            int t = i >> 8, d = i & 255;
            E[i] = u2f(src[(size_t)t * 512 + half * 256 + d]);
        }
        __syncthreads();
        for (int u = 0; u < 5; ++u) {
            int i = tid + 256 * u;
            if (i < 1089) {
                int r = i / 33, c = i % 33;
                const float* pr = &E[r * 256];
                const float* pc = &E[c * 256];
                float a = accv[u];
                for (int d = 0; d < 256; d += 4) {
                    float4 x = *(const float4*)&pr[d];
                    float4 y = *(const float4*)&pc[d];
                    a = fmaf(x.x, y.x, fmaf(x.y, y.y, fmaf(x.z, y.z, fmaf(x.w, y.w, a))));
                }
                accv[u] = a;
            }
        }
        __syncthreads();
    }
    for (int u = 0; u < 5; ++u) {
        int i = tid + 256 * u;
        if (i < 1089) rel[(size_t)b * 1152 + i] = f2u(accv[u]);
    }
    for (int i = 1089 + tid; i < 1152; i += 256) rel[(size_t)b * 1152 + i] = 0;
}

// ---------------------------------------------------------------------------
// Classifier head: bf16 cin (512 x 4224), fp32 W (4224 x 32) + sigmoid.
// ---------------------------------------------------------------------------
__global__ __launch_bounds__(256) void cls_k(
    const ushort_t* __restrict__ cin, const float* __restrict__ W,
    const float* __restrict__ bias, float* __restrict__ out)
{
    const int b = blockIdx.x, tid = threadIdx.x;
    const int n = tid & 31, kg = tid >> 5;
    const ushort_t* x = cin + (size_t)b * 4224;
    float acc = 0.f;
    for (int k = kg; k < 4224; k += 8)
        acc = fmaf(u2f(x[k]), W[(size_t)k * 32 + n], acc);

    __shared__ float part[8][32];
    part[kg][n] = acc;
    __syncthreads();
    if (tid < 32) {
        float s = bias[tid];
#pragma unroll
        for (int g = 0; g < 8; ++g) s += part[g][tid];
        out[(size_t)b * 32 + tid] = 1.f / (1.f + __expf(-s));
    }
}

// ---------------------------------------------------------------------------
// Host orchestration
// ---------------------------------------------------------------------------
extern "C" void kernel_launch(void* const* d_in, const int* in_sizes, int n_in,
                              void* d_out, int out_size, void* d_ws, size_t ws_size,
                              hipStream_t stream)
{
    const float* visual   = (const float*)d_in[0];
    const float* entity   = (const float*)d_in[1];
    const float* graph    = (const float*)d_in[2];
    const float* vis_W    = (const float*)d_in[3];
    const float* vis_b    = (const float*)d_in[4];
    const float* ent_W    = (const float*)d_in[5];
    const float* ent_b    = (const float*)d_in[6];
    const float* ca_Wq    = (const float*)d_in[7];
    const float* ca_bq    = (const float*)d_in[8];
    const float* ca_Wk    = (const float*)d_in[9];
    const float* ca_bk    = (const float*)d_in[10];
    const float* ca_Wv    = (const float*)d_in[11];
    const float* ca_bv    = (const float*)d_in[12];
    const float* ca_Wo    = (const float*)d_in[13];
    const float* ca_bo    = (const float*)d_in[14];
    const float* kp_W     = (const float*)d_in[15];
    const float* kp_b     = (const float*)d_in[16];
    const float* pred_W   = (const float*)d_in[17];
    const float* pred_b   = (const float*)d_in[18];
    const float* l_Wq     = (const float*)d_in[19];
    const float* l_bq     = (const float*)d_in[20];
    const float* l_Wk     = (const float*)d_in[21];
    const float* l_bk     = (const float*)d_in[22];
    const float* l_Wv     = (const float*)d_in[23];
    const float* l_bv     = (const float*)d_in[24];
    const float* l_Wo     = (const float*)d_in[25];
    const float* l_bo     = (const float*)d_in[26];
    const float* l_ffW1   = (const float*)d_in[27];
    const float* l_ffb1   = (const float*)d_in[28];
    const float* l_ffW2   = (const float*)d_in[29];
    const float* l_ffb2   = (const float*)d_in[30];
    const float* l_n1_g   = (const float*)d_in[31];
    const float* l_n1_b   = (const float*)d_in[32];
    const float* l_n2_g   = (const float*)d_in[33];
    const float* l_n2_b   = (const float*)d_in[34];
    const float* fin_g    = (const float*)d_in[35];
    const float* fin_b    = (const float*)d_in[36];
    const float* ad_W1    = (const float*)d_in[37];
    const float* ad_b1    = (const float*)d_in[38];
    const float* ad_W2    = (const float*)d_in[39];
    const float* ad_b2    = (const float*)d_in[40];
    const float* sc_fc_W  = (const float*)d_in[41];
    const float* sc_fc_b  = (const float*)d_in[42];
    const float* sc_cls_W = (const float*)d_in[43];
    const float* sc_cls_b = (const float*)d_in[44];

    const int B  = 512;
    const int Mv = B * 24;   // 12288
    const int Me = B * 33;   // 16896

    // ---- workspace layout
    char* wsb = (char*)d_ws;
    size_t off = 0;
    auto alloc_us = [&](size_t elems) -> ushort_t* {
        ushort_t* p = (ushort_t*)(wsb + off); off += ((elems * 2 + 255) & ~(size_t)255); return p; };
    auto alloc_f = [&](size_t elems) -> float* {
        float* p = (float*)(wsb + off); off += ((elems * 4 + 255) & ~(size_t)255); return p; };

    // weight (bf16, transposed) region
    ushort_t* vis_Wt = alloc_us((size_t)512 * 2048);
    ushort_t* ent_Wt = alloc_us((size_t)512 * 4096);
    ushort_t* caq_t  = alloc_us((size_t)512 * 512);
    ushort_t* cak_t  = alloc_us((size_t)512 * 512);   // + cav_t contiguous => fused KV
    ushort_t* cav_t  = alloc_us((size_t)512 * 512);
    ushort_t* cao_t  = alloc_us((size_t)512 * 512);
    ushort_t* kp_t   = alloc_us((size_t)512 * 512);
    ushort_t* pred_t = alloc_us((size_t)1089 * 1152);
    ushort_t* lw_t   = alloc_us((size_t)18 * 512 * 512);   // [layer*6 + slot]; slots k,v adjacent
    ushort_t* ad1_t  = alloc_us((size_t)512 * 512);
    ushort_t* ad2_t  = alloc_us((size_t)4096 * 512);
    ushort_t* fc_t   = alloc_us((size_t)128 * 512);

    // fp32 buffers
    float* o_x   = alloc_f((size_t)Me * 512);
    float* o_adj = alloc_f((size_t)B * 1089);

    // bf16 activation buffers
    ushort_t* o_xb  = alloc_us((size_t)Me * 512);
    ushort_t* o_xn  = alloc_us((size_t)Me * 512);
    ushort_t* o_q   = alloc_us((size_t)Me * 512);
    ushort_t* o_kv  = alloc_us((size_t)Me * 1024);   // fused K|V, ld 1024
    ushort_t* o_v   = alloc_us((size_t)Mv * 512);
    ushort_t* o_rel = alloc_us((size_t)B * 1152);
    ushort_t* o_cls = alloc_us((size_t)Me * 128);

    // optional bf16 copies of the big fp32 activations (guarded by ws_size)
    ushort_t* vis_a = alloc_us((size_t)Mv * 2048);
    ushort_t* ent_a = alloc_us((size_t)Me * 4096);
    const bool pre = (off <= ws_size);

    float* out_adapted = (float*)d_out;
    float* out_cls     = out_adapted + (size_t)Me * 4096;

    // ---- weight conversion jobs
    WJobs J; int nb = 0, ji = 0;
    auto addjob = [&](const float* src, ushort_t* dst, int K, int N, int Kd) {
        J.j[ji].src = src; J.j[ji].dst = dst; J.j[ji].K = K; J.j[ji].N = N;
        J.j[ji].Kd = Kd; J.j[ji].block0 = nb;
        nb += ((Kd + 31) / 32) * ((N + 31) / 32);
        ++ji;
    };
    addjob(vis_W, vis_Wt, 2048, 512, 2048);
    addjob(ent_W, ent_Wt, 4096, 512, 4096);
    addjob(ca_Wq, caq_t, 512, 512, 512);
    addjob(ca_Wk, cak_t, 512, 512, 512);
    addjob(ca_Wv, cav_t, 512, 512, 512);
    addjob(ca_Wo, cao_t, 512, 512, 512);
    addjob(kp_W,  kp_t,  512, 512, 512);
    addjob(pred_W, pred_t, 1089, 1089, 1152);
    for (int i = 0; i < 3; ++i) {
        addjob(l_Wq   + (size_t)i * 262144, lw_t + (size_t)(i * 6 + 0) * 262144, 512, 512, 512);
        addjob(l_Wk   + (size_t)i * 262144, lw_t + (size_t)(i * 6 + 1) * 262144, 512, 512, 512);
        addjob(l_Wv   + (size_t)i * 262144, lw_t + (size_t)(i * 6 + 2) * 262144, 512, 512, 512);
        addjob(l_Wo   + (size_t)i * 262144, lw_t + (size_t)(i * 6 + 3) * 262144, 512, 512, 512);
        addjob(l_ffW1 + (size_t)i * 262144, lw_t + (size_t)(i * 6 + 4) * 262144, 512, 512, 512);
        addjob(l_ffW2 + (size_t)i * 262144, lw_t + (size_t)(i * 6 + 5) * 262144, 512, 512, 512);
    }
    addjob(ad_W1, ad1_t, 512, 512, 512);
    addjob(ad_W2, ad2_t, 512, 4096, 512);
    addjob(sc_fc_W, fc_t, 512, 128, 512);
    J.n = ji;

    dim3 blk(256);
    wcvt_k<<<dim3(nb), blk, 0, stream>>>(J);

    auto g2 = [](int M, int N) { return dim3((unsigned)((N + 127) / 128), (unsigned)(M / 128)); };
    dim3 attn_grid(8, B);

    // ---- input projections
    if (pre) {
        f2b_k<<<dim3(2048), blk, 0, stream>>>(visual, vis_a, (unsigned)((size_t)Mv * 2048 / 8));
        f2b_k<<<dim3(2048), blk, 0, stream>>>(entity, ent_a, (unsigned)((size_t)Me * 4096 / 8));
        mfma_gemm<0, false, true, false, false><<<g2(Mv, 512), blk, 0, stream>>>(
            vis_a, 2048, vis_Wt, 2048, vis_b, nullptr, nullptr, nullptr, o_v, Mv, 512, 2048);
        mfma_gemm<0, false, true, false, false><<<g2(Me, 512), blk, 0, stream>>>(
            ent_a, 4096, ent_Wt, 4096, ent_b, nullptr, nullptr, nullptr, o_xn, Me, 512, 4096);
    } else {
        mfma_gemm<0, true, true, false, false><<<g2(Mv, 512), blk, 0, stream>>>(
            visual, 2048, vis_Wt, 2048, vis_b, nullptr, nullptr, nullptr, o_v, Mv, 512, 2048);
        mfma_gemm<0, true, true, false, false><<<g2(Me, 512), blk, 0, stream>>>(
            entity, 4096, ent_Wt, 4096, ent_b, nullptr, nullptr, nullptr, o_xn, Me, 512, 4096);
    }

    // ---- cross attention (KV fused: N=1024, Bt = cak_t|cav_t)
    mfma_gemm<0, false, true, false, false><<<g2(Me, 512), blk, 0, stream>>>(
        o_xn, 512, caq_t, 512, ca_bq, nullptr, nullptr, nullptr, o_q, Me, 512, 512);
    mfma_gemm<0, false, true, false, true><<<g2(Mv, 1024), blk, 0, stream>>>(
        o_v, 512, cak_t, 512, ca_bk, ca_bv, nullptr, nullptr, o_kv, Mv, 1024, 512);
    cross_attn_k<<<attn_grid, blk, 0, stream>>>(o_q, o_kv, o_xn);   // attc -> o_xn
    mfma_gemm<0, false, true, true, false><<<g2(Me, 512), blk, 0, stream>>>(
        o_xn, 512, cao_t, 512, ca_bo, nullptr, nullptr, o_x, o_xb, Me, 512, 512); // ef -> x (f32+bf16)

    // ---- knowledge path
    mfma_gemm<0, false, true, false, false><<<g2(Me, 512), blk, 0, stream>>>(
        o_xb, 512, kp_t, 512, kp_b, nullptr, nullptr, nullptr, o_q, Me, 512, 512);            // er
    rel_k<<<dim3(B), blk, 0, stream>>>(o_q, o_rel);
    mfma_gemm<4, false, false, true, false><<<g2(512, 1089), blk, 0, stream>>>(
        o_rel, 1152, pred_t, 1152, pred_b, nullptr, graph, o_adj, nullptr, 512, 1089, 1152);  // adj

    // ---- 3 transformer layers
    for (int i = 0; i < 3; ++i) {
        const ushort_t* Wq  = lw_t + (size_t)(i * 6 + 0) * 262144;
        const ushort_t* Wkv = lw_t + (size_t)(i * 6 + 1) * 262144;   // k|v adjacent slots
        const ushort_t* Wo  = lw_t + (size_t)(i * 6 + 3) * 262144;
        const ushort_t* W1  = lw_t + (size_t)(i * 6 + 4) * 262144;
        const ushort_t* W2  = lw_t + (size_t)(i * 6 + 5) * 262144;

        ln_k<<<dim3(Me), blk, 0, stream>>>(o_x, l_n1_g + (size_t)i * 512, l_n1_b + (size_t)i * 512, o_xn);
        mfma_gemm<0, false, true, false, false><<<g2(Me, 512), blk, 0, stream>>>(
            o_xn, 512, Wq, 512, l_bq + (size_t)i * 512, nullptr, nullptr, nullptr, o_q, Me, 512, 512);
        mfma_gemm<0, false, true, false, true><<<g2(Me, 1024), blk, 0, stream>>>(
            o_xb, 512, Wkv, 512, l_bk + (size_t)i * 512, l_bv + (size_t)i * 512,
            nullptr, nullptr, o_kv, Me, 1024, 512);
        self_attn_k<<<attn_grid, blk, 0, stream>>>(o_q, o_kv, o_adj, o_xn);
        mfma_gemm<2, false, true, true, false><<<g2(Me, 512), blk, 0, stream>>>(
            o_xn, 512, Wo, 512, l_bo + (size_t)i * 512, nullptr, o_x, o_x, o_xb, Me, 512, 512);   // x += att
        ln_k<<<dim3(Me), blk, 0, stream>>>(o_x, l_n2_g + (size_t)i * 512, l_n2_b + (size_t)i * 512, o_xn);
        mfma_gemm<1, false, true, false, false><<<g2(Me, 512), blk, 0, stream>>>(
            o_xn, 512, W1, 512, l_ffb1 + (size_t)i * 512, nullptr, nullptr, nullptr, o_q, Me, 512, 512); // relu
        mfma_gemm<2, false, true, true, false><<<g2(Me, 512), blk, 0, stream>>>(
            o_q, 512, W2, 512, l_ffb2 + (size_t)i * 512, nullptr, o_x, o_x, o_xb, Me, 512, 512);  // x += ff
    }

    // ---- final LN + heads
    ln_k<<<dim3(Me), blk, 0, stream>>>(o_x, fin_g, fin_b, o_xn);   // emb
    mfma_gemm<0, false, true, false, false><<<g2(Me, 512), blk, 0, stream>>>(
        o_xn, 512, ad1_t, 512, ad_b1, nullptr, nullptr, nullptr, o_q, Me, 512, 512);
    mfma_gemm<0, false, false, true, false><<<g2(Me, 4096), blk, 0, stream>>>(
        o_q, 512, ad2_t, 512, ad_b2, nullptr, nullptr, out_adapted, nullptr, Me, 4096, 512);
    mfma_gemm<0, false, true, false, false><<<g2(Me, 128), blk, 0, stream>>>(
        o_xn, 512, fc_t, 512, sc_fc_b, nullptr, nullptr, nullptr, o_cls, Me, 128, 512);
    cls_k<<<dim3(B), blk, 0, stream>>>(o_cls, sc_cls_W, sc_cls_b, out_cls);
}